// Round 6
// baseline (283.590 us; speedup 1.0000x reference)
//
#include <hip/hip_runtime.h>
#include <hip/hip_cooperative_groups.h>
#include <stdint.h>

namespace cg = cooperative_groups;

typedef unsigned long long u64;
typedef __attribute__((ext_vector_type(8))) short short8;   // 8 x bf16 (4 VGPR)
typedef __attribute__((ext_vector_type(4))) float f32x4;    // MFMA C/D frag

#define B_ 32
#define N_ 512
#define FIN_ 80
#define FH_ 50
#define NH_ 3
#define FO_ 80
#define CAT_ 150
#define KP_ 160   // padded K for layer-2 GEMM
#define NP_ 96    // padded N for layer-2 (80 cols + 15 zero + 1 ones)
#define GRID_ 512

__device__ inline unsigned short f2bf(float f) {  // RNE float -> bf16 bits
  unsigned u = __float_as_uint(f);
  u += 0x7fffu + ((u >> 16) & 1u);
  return (unsigned short)(u >> 16);
}

__device__ inline void fma4(float4& a, float s, const float4& w) {
  a.x += s * w.x; a.y += s * w.y; a.z += s * w.z; a.w += s * w.w;
}

// A-fragment builder: p = exp(min(lrelu(e1+e2),60)) masked, bf16
__device__ inline short8 build_af(const float* e2s, float e1r, u64 word,
                                  int jb, int shift) {
  short8 af;
  unsigned b0 = (unsigned)(word >> shift) & 0xffu;
  float4 va = *(const float4*)&e2s[jb];
  float4 vb = *(const float4*)&e2s[jb + 4];
  float ev[8] = {va.x, va.y, va.z, va.w, vb.x, vb.y, vb.z, vb.w};
  #pragma unroll
  for (int e = 0; e < 8; ++e) {
    float sv = e1r + ev[e];
    sv = fmaxf(sv, 0.2f * sv);
    sv = fminf(sv, 60.f);
    float arg = ((b0 >> e) & 1u) ? sv : -1e30f;
    af[e] = (short)f2bf(__expf(arg));
  }
  return af;
}

// ---------- P1 body: Wh = h @ Ws[h]; e1h/e2h f32; whT bf16 [col64][j512], col63=1 --
__device__ inline void k1_body(int task, const float* __restrict__ h,
                               const float* __restrict__ Ws,
                               const float* __restrict__ attn_a,
                               unsigned short* __restrict__ whT,
                               float* __restrict__ e1h, float* __restrict__ e2h,
                               char* smem) {
  float* hs  = (float*)smem;            // 64*84 f32 (stride 84: 2-way banks)
  float* wsl = (float*)(smem + 21504);  // 80*64 f32
  float* a1s = (float*)(smem + 41984);  // 64 f32
  float* a2s = (float*)(smem + 42240);  // 64 f32
  int x = task;
  const int rt = x & 7; x >>= 3;
  const int bb = x & 31; x >>= 5;
  const int hh = x;  // 0..2
  const int n0 = rt * 64;
  const int t = threadIdx.x;

  {
    const float4* src = (const float4*)(h + ((size_t)bb * N_ + n0) * FIN_);
    for (int i = t; i < 64 * 20; i += 256) {
      int row = i / 20, kq = i % 20;
      *(float4*)&hs[row * 84 + kq * 4] = src[row * 20 + kq];
    }
  }
  {
    const float* src = Ws + (size_t)hh * FIN_ * FH_;
    for (int i = t; i < FIN_ * 64; i += 256) {
      int k = i >> 6, c = i & 63;
      wsl[i] = (c < FH_) ? src[k * FH_ + c] : 0.0f;
    }
  }
  if (t < 64) {
    a1s[t] = (t < FH_) ? attn_a[hh * 2 * FH_ + t] : 0.0f;
    a2s[t] = (t < FH_) ? attn_a[hh * 2 * FH_ + FH_ + t] : 0.0f;
  }
  __syncthreads();

  const int r = t >> 2, cq = t & 3;
  float4 acc[4];
  for (int i = 0; i < 4; ++i) acc[i] = make_float4(0.f, 0.f, 0.f, 0.f);
  const float4* ws4 = (const float4*)wsl;
  #pragma unroll 4
  for (int k = 0; k < FIN_; ++k) {
    float hv = hs[r * 84 + k];
    #pragma unroll
    for (int i = 0; i < 4; ++i) fma4(acc[i], hv, ws4[k * 16 + cq * 4 + i]);
  }
  {
    const float4* a14 = (const float4*)a1s;
    const float4* a24 = (const float4*)a2s;
    float p1 = 0.f, p2 = 0.f;
    #pragma unroll
    for (int i = 0; i < 4; ++i) {
      float4 a1 = a14[cq * 4 + i], a2 = a24[cq * 4 + i], v = acc[i];
      p1 += v.x * a1.x + v.y * a1.y + v.z * a1.z + v.w * a1.w;
      p2 += v.x * a2.x + v.y * a2.y + v.z * a2.z + v.w * a2.w;
    }
    p1 += __shfl_xor(p1, 1); p1 += __shfl_xor(p1, 2);
    p2 += __shfl_xor(p2, 1); p2 += __shfl_xor(p2, 2);
    if (cq == 0) {
      size_t o = ((size_t)hh * B_ + bb) * N_ + n0 + r;
      e1h[o] = p1; e2h[o] = p2;
    }
  }
  __syncthreads();
  float* tb = hs;  // reuse as tb[j][col], 64x64
  {
    float4* trow = (float4*)(tb + r * 64);
    #pragma unroll
    for (int i = 0; i < 4; ++i) trow[cq * 4 + i] = acc[i];
  }
  __syncthreads();
  for (int g = t; g < 512; g += 256) {
    const int col = g >> 3, jg = g & 7;
    unsigned short pk[8];
    #pragma unroll
    for (int e = 0; e < 8; ++e)
      pk[e] = (col == 63) ? (unsigned short)0x3f80 : f2bf(tb[(jg * 8 + e) * 64 + col]);
    uint4 o;
    o.x = (unsigned)pk[0] | ((unsigned)pk[1] << 16);
    o.y = (unsigned)pk[2] | ((unsigned)pk[3] << 16);
    o.z = (unsigned)pk[4] | ((unsigned)pk[5] << 16);
    o.w = (unsigned)pk[6] | ((unsigned)pk[7] << 16);
    *(uint4*)&whT[(((size_t)hh * B_ + bb) * 64 + col) * 512 + n0 + jg * 8] = o;
  }
  __syncthreads();  // hs reused on next task
}

// ---------- P1 body: adj -> bitmask (8 row-groups per block) ----------------------
__device__ inline void mask_body(int bid, const int* __restrict__ adj,
                                 u64* __restrict__ maskw) {
  const int t = threadIdx.x;
  const int wid = t >> 6, l = t & 63;
  #pragma unroll
  for (int rr = 0; rr < 8; ++rr) {
    const int row = (rr * GRID_ + bid) * 4 + wid;  // covers 16384 rows
    const int* src = adj + (size_t)row * N_;
    u64* dst = maskw + (size_t)row * 8;
    #pragma unroll
    for (int it = 0; it < 8; ++it) {
      int v = src[it * 64 + l];
      u64 m = __ballot(v != 0);
      if (l == 0) dst[it] = m;
    }
  }
}

// ---------- P1 body: WoutT bf16 [96][160] + wv1/wv2 f32 (one block) ---------------
__device__ inline void wprep_body(const float* __restrict__ Wout,
                                  const float* __restrict__ a_out,
                                  unsigned short* __restrict__ WoutT,
                                  float* __restrict__ wv1, float* __restrict__ wv2) {
  const int t = threadIdx.x;
  for (int i = t; i < NP_ * KP_ / 4; i += 256) {
    int base = i * 4;
    int col = base / KP_, k0 = base % KP_;
    unsigned short pk[4];
    #pragma unroll
    for (int e = 0; e < 4; ++e) {
      int k = k0 + e;
      pk[e] = (col < FO_ && k < CAT_) ? f2bf(Wout[(size_t)k * FO_ + col]) : 0;
    }
    uint2 o;
    o.x = (unsigned)pk[0] | ((unsigned)pk[1] << 16);
    o.y = (unsigned)pk[2] | ((unsigned)pk[3] << 16);
    ((uint2*)WoutT)[i] = o;
  }
  for (int k = t; k < CAT_; k += 256) {
    const float4* wr = (const float4*)(Wout + (size_t)k * FO_);
    const float4* a1 = (const float4*)a_out;
    const float4* a2 = (const float4*)(a_out + FO_);
    float p1 = 0.f, p2 = 0.f;
    #pragma unroll
    for (int i = 0; i < 20; ++i) {
      float4 v = wr[i], x1 = a1[i], x2 = a2[i];
      p1 += v.x * x1.x + v.y * x1.y + v.z * x1.z + v.w * x1.w;
      p2 += v.x * x2.x + v.y * x2.y + v.z * x2.z + v.w * x2.w;
    }
    wv1[k] = p1; wv2[k] = p2;
  }
}

// ---------- P2 body: layer-1 attention -> catbf bf16 + per-head e-partials --------
__device__ inline void k3_body(int task, const unsigned short* __restrict__ whT,
                               const float* __restrict__ e1, const float* __restrict__ e2,
                               const u64* __restrict__ maskw,
                               const float* __restrict__ wv1, const float* __restrict__ wv2,
                               unsigned short* __restrict__ catbf,
                               float* __restrict__ e1p, float* __restrict__ e2p,
                               char* smem) {
  float* e2s = (float*)smem;  // 512 f32
  int x = (int)((task & 7) * 96 + (task >> 3));  // XCD-ish swizzle over 768 tasks
  const int rt = x & 7; x >>= 3;
  const int bb = x & 31; x >>= 5;
  const int hh = x;
  const int n0 = rt * 64;
  const int t = threadIdx.x;
  const int l = t & 63, wid = t >> 6;
  const int q = l >> 4, rl = l & 15;

  const float* e2pp = e2 + ((size_t)hh * B_ + bb) * N_;
  for (int i = t; i < N_ / 4; i += 256) ((float4*)e2s)[i] = ((const float4*)e2pp)[i];
  __syncthreads();

  const int row = n0 + wid * 16 + rl;
  const float e1r = e1[((size_t)hh * B_ + bb) * N_ + row];
  const u64* mr = maskw + ((size_t)bb * N_ + row) * 8;

  f32x4 acc[4];
  #pragma unroll
  for (int c = 0; c < 4; ++c) acc[c] = (f32x4){0.f, 0.f, 0.f, 0.f};
  const unsigned short* wb = whT + ((size_t)hh * B_ + bb) * 64 * 512;

  for (int tt = 0; tt < 8; ++tt) {
    short8 bf[4][2];
    #pragma unroll
    for (int c = 0; c < 4; ++c) {
      const unsigned short* bp = wb + (size_t)(c * 16 + rl) * 512 + tt * 64 + q * 8;
      bf[c][0] = *(const short8*)bp;
      bf[c][1] = *(const short8*)(bp + 32);
    }
    u64 word = mr[tt];
    short8 af0 = build_af(e2s, e1r, word, tt * 64 + q * 8, q * 8);
    short8 af1 = build_af(e2s, e1r, word, tt * 64 + 32 + q * 8, 32 + q * 8);
    #pragma unroll
    for (int c = 0; c < 4; ++c) {
      acc[c] = __builtin_amdgcn_mfma_f32_16x16x32_bf16(af0, bf[c][0], acc[c], 0, 0, 0);
      acc[c] = __builtin_amdgcn_mfma_f32_16x16x32_bf16(af1, bf[c][1], acc[c], 0, 0, 0);
    }
  }

  float w1c[4], w2c[4];
  #pragma unroll
  for (int c = 0; c < 4; ++c) {
    const int col = c * 16 + rl;
    w1c[c] = (col < FH_) ? wv1[hh * FH_ + col] : 0.f;
    w2c[c] = (col < FH_) ? wv2[hh * FH_ + col] : 0.f;
  }

  const size_t orow0 = (size_t)bb * N_ + n0 + wid * 16;
  #pragma unroll
  for (int r = 0; r < 4; ++r) {
    float srow = __shfl(acc[3][r], (q << 4) | 15);  // col 63 = denom (ones col)
    float invr = srow > 0.f ? 1.f / srow : 0.f;
    const size_t grow = orow0 + q * 4 + r;
    float p1 = 0.f, p2 = 0.f;
    #pragma unroll
    for (int c = 0; c < 4; ++c) {
      const int col = c * 16 + rl;
      if (col < FH_) {
        float v = acc[c][r] * invr;
        v = v > 0.f ? v : __expf(v) - 1.f;  // ELU
        catbf[grow * KP_ + hh * FH_ + col] = f2bf(v);
        p1 += v * w1c[c];
        p2 += v * w2c[c];
      }
    }
    p1 += __shfl_xor(p1, 1); p1 += __shfl_xor(p1, 2);
    p1 += __shfl_xor(p1, 4); p1 += __shfl_xor(p1, 8);
    p2 += __shfl_xor(p2, 1); p2 += __shfl_xor(p2, 2);
    p2 += __shfl_xor(p2, 4); p2 += __shfl_xor(p2, 8);
    if (rl == 0) {
      e1p[(size_t)hh * (B_ * N_) + grow] = p1;
      e2p[(size_t)hh * (B_ * N_) + grow] = p2;
    }
  }
  if (hh == 2 && t < 64) {  // zero-pad K cols 150..159
    const size_t grow = (size_t)bb * N_ + n0 + t;
    unsigned* zp = (unsigned*)&catbf[grow * KP_ + CAT_];
    #pragma unroll
    for (int i = 0; i < 5; ++i) zp[i] = 0u;
  }
  __syncthreads();  // e2s reused on next task
}

// ---------- P3 body: Wh2 = catbf @ WoutT via MFMA (cols 0..79); fill 80..95 -------
__device__ inline void k4_body(int blk, const unsigned short* __restrict__ catbf,
                               const unsigned short* __restrict__ WoutT,
                               unsigned short* __restrict__ wh2T) {
  const int t = threadIdx.x, l = t & 63, wid = t >> 6;
  const int q = l >> 4, rl = l & 15;
  const int jbase = blk * 64 + wid * 16;
  f32x4 acc[5];
  #pragma unroll
  for (int nt = 0; nt < 5; ++nt) acc[nt] = (f32x4){0.f, 0.f, 0.f, 0.f};
  const unsigned short* ap = catbf + (size_t)(jbase + rl) * KP_ + q * 8;
  #pragma unroll
  for (int kk = 0; kk < 5; ++kk) {
    short8 a = *(const short8*)(ap + kk * 32);
    #pragma unroll
    for (int nt = 0; nt < 5; ++nt) {
      short8 b = *(const short8*)&WoutT[(size_t)(nt * 16 + rl) * KP_ + kk * 32 + q * 8];
      acc[nt] = __builtin_amdgcn_mfma_f32_16x16x32_bf16(a, b, acc[nt], 0, 0, 0);
    }
  }
  const int bb = blk >> 3, jt = blk & 7;
  const int j0 = jt * 64 + wid * 16 + q * 4;
  #pragma unroll
  for (int nt = 0; nt < 5; ++nt) {
    const int col = nt * 16 + rl;
    unsigned short pk[4];
    #pragma unroll
    for (int r = 0; r < 4; ++r) pk[r] = f2bf(acc[nt][r]);
    uint2 o;
    o.x = (unsigned)pk[0] | ((unsigned)pk[1] << 16);
    o.y = (unsigned)pk[2] | ((unsigned)pk[3] << 16);
    *(uint2*)&wh2T[((size_t)bb * NP_ + col) * 512 + j0] = o;
  }
  {
    const int col = 80 + (t >> 4), jq = (t & 15) * 4;
    unsigned fill = (col == 95) ? 0x3f803f80u : 0u;
    uint2 o; o.x = fill; o.y = fill;
    *(uint2*)&wh2T[((size_t)bb * NP_ + col) * 512 + jt * 64 + jq] = o;
  }
}

// ---------- P4 body: layer-2 attention, j-split across 4 waves --------------------
__device__ inline void k5_body(int task, const unsigned short* __restrict__ wh2T,
                               const float* __restrict__ e1p, const float* __restrict__ e2p,
                               const u64* __restrict__ maskw, float* __restrict__ out,
                               char* smem) {
  float* e2s = (float*)smem;                   // 512 f32
  float* red = (float*)(smem + 2048);          // [4][64][25] f32
  int x = (int)((task & 7) * 128 + (task >> 3));  // swizzle over 1024 tasks
  const int rg = x & 31;
  const int bb = x >> 5;
  const int n0 = rg * 16;
  const int t = threadIdx.x;
  const int l = t & 63, wid = t >> 6;
  const int q = l >> 4, rl = l & 15;

  for (int i = t; i < N_ / 4; i += 256) {
    float4 v0 = ((const float4*)(e2p))[(size_t)bb * 128 + i];
    float4 v1 = ((const float4*)(e2p + B_ * N_))[(size_t)bb * 128 + i];
    float4 v2 = ((const float4*)(e2p + 2 * B_ * N_))[(size_t)bb * 128 + i];
    float4 s;
    s.x = v0.x + v1.x + v2.x; s.y = v0.y + v1.y + v2.y;
    s.z = v0.z + v1.z + v2.z; s.w = v0.w + v1.w + v2.w;
    ((float4*)e2s)[i] = s;
  }
  __syncthreads();

  const int row = n0 + rl;
  const size_t gr = (size_t)bb * N_ + row;
  const float e1r = e1p[gr] + e1p[B_ * N_ + gr] + e1p[2 * B_ * N_ + gr];
  const u64* mr = maskw + gr * 8;

  f32x4 acc[6];
  #pragma unroll
  for (int c = 0; c < 6; ++c) acc[c] = (f32x4){0.f, 0.f, 0.f, 0.f};
  const unsigned short* wb = wh2T + (size_t)bb * NP_ * 512;

  #pragma unroll
  for (int tts = 0; tts < 2; ++tts) {
    const int tt = wid * 2 + tts;
    short8 bf[6][2];
    #pragma unroll
    for (int c = 0; c < 6; ++c) {
      const unsigned short* bp = wb + (size_t)(c * 16 + rl) * 512 + tt * 64 + q * 8;
      bf[c][0] = *(const short8*)bp;
      bf[c][1] = *(const short8*)(bp + 32);
    }
    u64 word = mr[tt];
    short8 af0 = build_af(e2s, e1r, word, tt * 64 + q * 8, q * 8);
    short8 af1 = build_af(e2s, e1r, word, tt * 64 + 32 + q * 8, 32 + q * 8);
    #pragma unroll
    for (int c = 0; c < 6; ++c) {
      acc[c] = __builtin_amdgcn_mfma_f32_16x16x32_bf16(af0, bf[c][0], acc[c], 0, 0, 0);
      acc[c] = __builtin_amdgcn_mfma_f32_16x16x32_bf16(af1, bf[c][1], acc[c], 0, 0, 0);
    }
  }

  #pragma unroll
  for (int c = 0; c < 6; ++c)
    #pragma unroll
    for (int r = 0; r < 4; ++r) red[(size_t)wid * 1600 + l * 25 + c * 4 + r] = acc[c][r];
  __syncthreads();

  if (wid == 0) {
    #pragma unroll
    for (int c = 0; c < 6; ++c)
      #pragma unroll
      for (int r = 0; r < 4; ++r) {
        const int idx = l * 25 + c * 4 + r;
        acc[c][r] = red[idx] + red[1600 + idx] + red[3200 + idx] + red[4800 + idx];
      }
    const size_t orow0 = (size_t)bb * N_ + n0;
    #pragma unroll
    for (int r = 0; r < 4; ++r) {
      float srow = __shfl(acc[5][r], (q << 4) | 15);  // col 95 = denom
      float invr = srow > 0.f ? 1.f / srow : 0.f;
      const size_t ob = (orow0 + q * 4 + r) * FO_;
      #pragma unroll
      for (int c = 0; c < 5; ++c) out[ob + c * 16 + rl] = acc[c][r] * invr;
    }
  }
  __syncthreads();  // red/e2s reused on next task
}

// ---------------- fused cooperative kernel ----------------------------------------
__global__ __launch_bounds__(256, 2) void fused(const float* __restrict__ h,
                                                const int* __restrict__ adj,
                                                const float* __restrict__ Ws,
                                                const float* __restrict__ aa,
                                                const float* __restrict__ Wout,
                                                const float* __restrict__ aout,
                                                char* __restrict__ ws,
                                                float* __restrict__ out) {
  __shared__ __align__(16) char smem[42496];
  unsigned short* whT   = (unsigned short*)(ws + 0);         // 6,291,456
  float* e1h            = (float*)(ws + 6291456);            //   196,608
  float* e2h            = (float*)(ws + 6488064);            //   196,608
  u64*   mk             = (u64*)  (ws + 6684672);            // 1,048,576
  unsigned short* catbf = (unsigned short*)(ws + 7733248);   // 5,242,880
  unsigned short* WoutT = (unsigned short*)(ws + 12976128);  //    30,720
  float* wv1            = (float*)(ws + 13008896);
  float* wv2            = (float*)(ws + 13009920);
  float* e1p            = (float*)(ws + 13010944);           //   196,608
  float* e2p            = (float*)(ws + 13207552);           //   196,608
  unsigned short* wh2T  = (unsigned short*)(ws + 13404160);  // 3,145,728

  const int bid = blockIdx.x;
  cg::grid_group grid = cg::this_grid();

  // P01: k1 tasks (768) + mask (all blocks) + Wout prep (block 511)
  for (int task = bid; task < 768; task += GRID_)
    k1_body(task, h, Ws, aa, whT, e1h, e2h, smem);
  mask_body(bid, adj, mk);
  if (bid == GRID_ - 1) wprep_body(Wout, aout, WoutT, wv1, wv2);
  grid.sync();

  // P2: layer-1 attention (768 tasks)
  for (int task = bid; task < 768; task += GRID_)
    k3_body(task, whT, e1h, e2h, mk, wv1, wv2, catbf, e1p, e2p, smem);
  grid.sync();

  // P3: layer-2 GEMM (256 tasks)
  if (bid < 256) k4_body(bid, catbf, WoutT, wh2T);
  grid.sync();

  // P4: layer-2 attention (1024 tasks)
  for (int task = bid; task < 1024; task += GRID_)
    k5_body(task, wh2T, e1p, e2p, mk, out, smem);
}

extern "C" void kernel_launch(void* const* d_in, const int* in_sizes, int n_in,
                              void* d_out, int out_size, void* d_ws, size_t ws_size,
                              hipStream_t stream) {
  const float* h    = (const float*)d_in[0];
  const int*   adj  = (const int*)d_in[1];
  const float* Ws   = (const float*)d_in[2];
  const float* aa   = (const float*)d_in[3];
  const float* Wout = (const float*)d_in[4];
  const float* aout = (const float*)d_in[5];
  char* wsb = (char*)d_ws;
  float* outp = (float*)d_out;

  void* args[] = {(void*)&h, (void*)&adj, (void*)&Ws, (void*)&aa,
                  (void*)&Wout, (void*)&aout, (void*)&wsb, (void*)&outp};
  hipLaunchCooperativeKernel((const void*)fused, dim3(GRID_), dim3(256), args, 0, stream);
}

// Round 7
// 95.779 us; speedup vs baseline: 2.9609x; 2.9609x over previous
//
#include <hip/hip_runtime.h>
#include <stdint.h>

typedef unsigned long long u64;
typedef __attribute__((ext_vector_type(8))) short short8;   // 8 x bf16 (4 VGPR)
typedef __attribute__((ext_vector_type(4))) float f32x4;    // MFMA C/D frag

#define B_ 32
#define N_ 512
#define FIN_ 80
#define FH_ 50
#define FO_ 80
#define CAT_ 150
#define KP_ 160   // padded K for layer-2 GEMM
#define NP_ 96    // padded N for layer-2 (80 cols + 15 zero + 1 ones)

__device__ inline unsigned short f2bf(float f) {  // RNE float -> bf16 bits
  unsigned u = __float_as_uint(f);
  u += 0x7fffu + ((u >> 16) & 1u);
  return (unsigned short)(u >> 16);
}

// A-fragment builder: p = exp(min(lrelu(e1+e2),60)) masked, bf16
__device__ inline short8 build_af(const float* e2s, float e1r, u64 word,
                                  int jb, int shift) {
  short8 af;
  unsigned b0 = (unsigned)(word >> shift) & 0xffu;
  float4 va = *(const float4*)&e2s[jb];
  float4 vb = *(const float4*)&e2s[jb + 4];
  float ev[8] = {va.x, va.y, va.z, va.w, vb.x, vb.y, vb.z, vb.w};
  #pragma unroll
  for (int e = 0; e < 8; ++e) {
    float sv = e1r + ev[e];
    sv = fmaxf(sv, 0.2f * sv);
    sv = fminf(sv, 60.f);
    float arg = ((b0 >> e) & 1u) ? sv : -1e30f;
    af[e] = (short)f2bf(__expf(arg));
  }
  return af;
}

// ---------- KA: blocks 0..767 = MFMA Wh-prep; 768..1279 = mask (1279 += Wout prep) --
__global__ __launch_bounds__(256) void kA(const float* __restrict__ h,
                                          const int* __restrict__ adj,
                                          const float* __restrict__ Ws,
                                          const float* __restrict__ attn_a,
                                          const float* __restrict__ Wout,
                                          const float* __restrict__ a_out,
                                          unsigned short* __restrict__ whT,
                                          float* __restrict__ e1h,
                                          float* __restrict__ e2h,
                                          u64* __restrict__ maskw,
                                          unsigned short* __restrict__ WoutT,
                                          float* __restrict__ wv1,
                                          float* __restrict__ wv2) {
  __shared__ __align__(16) unsigned short hsb[64 * 104];   // bf16 h-tile, k padded to 96(+8)
  __shared__ __align__(16) unsigned short bstage[12 * 512]; // B-frags [ks*4+nt][lane][8]
  __shared__ __align__(16) float wa1s[96];
  __shared__ __align__(16) float wa2s[96];
  __shared__ __align__(16) unsigned short tbT[64 * 72];    // [col][j] bf16, stride 72
  const int t = threadIdx.x;
  const int bid = blockIdx.x;

  if (bid >= 768) {  // ---- mask blocks ----
    const int mb = bid - 768;
    const int wid = t >> 6, l = t & 63;
    #pragma unroll
    for (int rr = 0; rr < 8; ++rr) {
      const int row = (rr * 512 + mb) * 4 + wid;  // 16384 rows total
      const int* src = adj + (size_t)row * N_;
      u64* dst = maskw + (size_t)row * 8;
      #pragma unroll
      for (int it = 0; it < 8; ++it) {
        int v = src[it * 64 + l];
        u64 m = __ballot(v != 0);
        if (l == 0) dst[it] = m;
      }
    }
    if (bid == 1279) {  // ---- Wout prep ----
      for (int i = t; i < NP_ * KP_ / 4; i += 256) {
        int base = i * 4;
        int col = base / KP_, k0 = base % KP_;
        unsigned short pk[4];
        #pragma unroll
        for (int e = 0; e < 4; ++e) {
          int k = k0 + e;
          pk[e] = (col < FO_ && k < CAT_) ? f2bf(Wout[(size_t)k * FO_ + col]) : 0;
        }
        uint2 o;
        o.x = (unsigned)pk[0] | ((unsigned)pk[1] << 16);
        o.y = (unsigned)pk[2] | ((unsigned)pk[3] << 16);
        ((uint2*)WoutT)[i] = o;
      }
      for (int k = t; k < CAT_; k += 256) {
        const float4* wr = (const float4*)(Wout + (size_t)k * FO_);
        const float4* a1 = (const float4*)a_out;
        const float4* a2 = (const float4*)(a_out + FO_);
        float p1 = 0.f, p2 = 0.f;
        #pragma unroll
        for (int i = 0; i < 20; ++i) {
          float4 v = wr[i], x1 = a1[i], x2 = a2[i];
          p1 += v.x * x1.x + v.y * x1.y + v.z * x1.z + v.w * x1.w;
          p2 += v.x * x2.x + v.y * x2.y + v.z * x2.z + v.w * x2.w;
        }
        wv1[k] = p1; wv2[k] = p2;
      }
    }
    return;
  }

  // ---- Wh-prep blocks: task = (hh, bb, rt), 64 rows each ----
  int x = bid;
  const int rt = x & 7; x >>= 3;
  const int bb = x & 31; x >>= 5;
  const int hh = x;
  const int n0 = rt * 64;
  const float* hblk = h + ((size_t)bb * N_ + n0) * FIN_;
  const float* wsrc = Ws + (size_t)hh * FIN_ * FH_;

  // stage h tile as bf16 (zero-pad k>=80)
  for (int idx = t; idx < 64 * 13; idx += 256) {
    const int row = idx / 13, kc8 = idx - row * 13, k0 = kc8 * 8;
    short8 v8;
    if (k0 < FIN_) {
      float4 a = *(const float4*)(hblk + row * FIN_ + k0);
      float4 b = *(const float4*)(hblk + row * FIN_ + k0 + 4);
      v8[0] = (short)f2bf(a.x); v8[1] = (short)f2bf(a.y);
      v8[2] = (short)f2bf(a.z); v8[3] = (short)f2bf(a.w);
      v8[4] = (short)f2bf(b.x); v8[5] = (short)f2bf(b.y);
      v8[6] = (short)f2bf(b.z); v8[7] = (short)f2bf(b.w);
    } else {
      #pragma unroll
      for (int e = 0; e < 8; ++e) v8[e] = 0;
    }
    *(short8*)&hsb[row * 104 + k0] = v8;
  }
  // wa1/wa2 = W @ a halves (f32, for exact e-path)
  if (t < 96) {
    float s1 = 0.f, s2 = 0.f;
    if (t < FIN_) {
      const float* wr = wsrc + t * FH_;
      const float* a1 = attn_a + hh * 2 * FH_;
      #pragma unroll 10
      for (int c = 0; c < FH_; ++c) { s1 += wr[c] * a1[c]; s2 += wr[c] * a1[FH_ + c]; }
    }
    wa1s[t] = s1; wa2s[t] = s2;
  }
  // B-fragments pre-swizzled: frag f=(ks*4+nt), lane lf: k=ks*32+(lf>>4)*8+e, n=nt*16+(lf&15)
  for (int idx = t; idx < 12 * 64; idx += 256) {
    const int f = idx >> 6, lf = idx & 63;
    const int ks = f >> 2, nt = f & 3;
    const int kb = ks * 32 + (lf >> 4) * 8, n = nt * 16 + (lf & 15);
    short8 v8;
    #pragma unroll
    for (int e = 0; e < 8; ++e) {
      const int k = kb + e;
      v8[e] = (k < FIN_ && n < FH_) ? (short)f2bf(wsrc[k * FH_ + n]) : (short)0;
    }
    *(short8*)&bstage[f * 512 + lf * 8] = v8;
  }
  __syncthreads();

  // e1/e2 exact: e = h_f32 . wa  (thread = row r, k-quarter cq)
  {
    const int r = t >> 2, cq = t & 3;
    const float* hr = hblk + r * FIN_ + cq * 20;
    const float4* w1 = (const float4*)&wa1s[cq * 20];
    const float4* w2 = (const float4*)&wa2s[cq * 20];
    float s1 = 0.f, s2 = 0.f;
    #pragma unroll
    for (int i = 0; i < 5; ++i) {
      float4 hv = *(const float4*)(hr + i * 4);
      float4 a = w1[i], b = w2[i];
      s1 += hv.x * a.x + hv.y * a.y + hv.z * a.z + hv.w * a.w;
      s2 += hv.x * b.x + hv.y * b.y + hv.z * b.z + hv.w * b.w;
    }
    s1 += __shfl_xor(s1, 1); s1 += __shfl_xor(s1, 2);
    s2 += __shfl_xor(s2, 1); s2 += __shfl_xor(s2, 2);
    if (cq == 0) {
      size_t o = ((size_t)hh * B_ + bb) * N_ + n0 + r;
      e1h[o] = s1; e2h[o] = s2;
    }
  }

  // MFMA: per wave 16 rows x 64 cols, K=96 (3 steps)
  {
    const int l = t & 63, wv = t >> 6, q = l >> 4, rl = l & 15;
    short8 af[3];
    #pragma unroll
    for (int ks = 0; ks < 3; ++ks)
      af[ks] = *(const short8*)&hsb[(wv * 16 + rl) * 104 + ks * 32 + q * 8];
    f32x4 acc[4];
    #pragma unroll
    for (int nt = 0; nt < 4; ++nt) acc[nt] = (f32x4){0.f, 0.f, 0.f, 0.f};
    #pragma unroll
    for (int ks = 0; ks < 3; ++ks)
      #pragma unroll
      for (int nt = 0; nt < 4; ++nt)
        acc[nt] = __builtin_amdgcn_mfma_f32_16x16x32_bf16(
            af[ks], *(const short8*)&bstage[(ks * 4 + nt) * 512 + l * 8], acc[nt], 0, 0, 0);
    // transpose-bounce: tbT[col][j]
    #pragma unroll
    for (int nt = 0; nt < 4; ++nt)
      #pragma unroll
      for (int r2 = 0; r2 < 4; ++r2)
        tbT[(nt * 16 + rl) * 72 + wv * 16 + q * 4 + r2] = f2bf(acc[nt][r2]);
  }
  __syncthreads();
  // emit whT[col][j] coalesced; col 63 = ones (denominator)
  {
    const int col = t & 63, half = t >> 6;
    uint4 o0 = *(const uint4*)&tbT[col * 72 + half * 16];
    uint4 o1 = *(const uint4*)&tbT[col * 72 + half * 16 + 8];
    if (col == 63) {
      o0.x = o0.y = o0.z = o0.w = 0x3f803f80u;
      o1 = o0;
    }
    unsigned short* dst = whT + (((size_t)hh * B_ + bb) * 64 + col) * 512 + n0 + half * 16;
    *(uint4*)dst = o0;
    *(uint4*)(dst + 8) = o1;
  }
}

// ---------- K3s: layer-1 attention, 16-row blocks, 4-wave j-split ------------------
__global__ __launch_bounds__(256) void k3s(const unsigned short* __restrict__ whT,
                                           const float* __restrict__ e1,
                                           const float* __restrict__ e2,
                                           const u64* __restrict__ maskw,
                                           const float* __restrict__ wv1,
                                           const float* __restrict__ wv2,
                                           unsigned short* __restrict__ catbf,
                                           float* __restrict__ e1p,
                                           float* __restrict__ e2p) {
  __shared__ __align__(16) float e2s[N_];
  __shared__ __align__(16) float red[4][64][17];
  int x = (int)((blockIdx.x & 7) * 384 + (blockIdx.x >> 3));  // bijective (3072%8==0)
  const int hh = x >> 10;
  const int bb = (x >> 5) & 31;
  const int rg = x & 31;
  const int n0 = rg * 16;
  const int t = threadIdx.x;
  const int l = t & 63, wid = t >> 6;
  const int q = l >> 4, rl = l & 15;

  const float* e2pp = e2 + ((size_t)hh * B_ + bb) * N_;
  for (int i = t; i < N_ / 4; i += 256) ((float4*)e2s)[i] = ((const float4*)e2pp)[i];
  __syncthreads();

  const int row = n0 + rl;
  const float e1r = e1[((size_t)hh * B_ + bb) * N_ + row];
  const u64* mr = maskw + ((size_t)bb * N_ + row) * 8;

  f32x4 acc[4];
  #pragma unroll
  for (int c = 0; c < 4; ++c) acc[c] = (f32x4){0.f, 0.f, 0.f, 0.f};
  const unsigned short* wb = whT + ((size_t)hh * B_ + bb) * 64 * 512;

  #pragma unroll
  for (int tts = 0; tts < 2; ++tts) {
    const int tt = wid * 2 + tts;
    short8 bf[4][2];
    #pragma unroll
    for (int c = 0; c < 4; ++c) {
      const unsigned short* bp = wb + (size_t)(c * 16 + rl) * 512 + tt * 64 + q * 8;
      bf[c][0] = *(const short8*)bp;
      bf[c][1] = *(const short8*)(bp + 32);
    }
    u64 word = mr[tt];
    short8 af0 = build_af(e2s, e1r, word, tt * 64 + q * 8, q * 8);
    short8 af1 = build_af(e2s, e1r, word, tt * 64 + 32 + q * 8, 32 + q * 8);
    #pragma unroll
    for (int c = 0; c < 4; ++c) {
      acc[c] = __builtin_amdgcn_mfma_f32_16x16x32_bf16(af0, bf[c][0], acc[c], 0, 0, 0);
      acc[c] = __builtin_amdgcn_mfma_f32_16x16x32_bf16(af1, bf[c][1], acc[c], 0, 0, 0);
    }
  }

  #pragma unroll
  for (int c = 0; c < 4; ++c)
    #pragma unroll
    for (int r = 0; r < 4; ++r) red[wid][l][c * 4 + r] = acc[c][r];
  __syncthreads();

  if (wid == 0) {
    #pragma unroll
    for (int c = 0; c < 4; ++c)
      #pragma unroll
      for (int r = 0; r < 4; ++r)
        acc[c][r] = red[0][l][c * 4 + r] + red[1][l][c * 4 + r] +
                    red[2][l][c * 4 + r] + red[3][l][c * 4 + r];
    float w1c[4], w2c[4];
    #pragma unroll
    for (int c = 0; c < 4; ++c) {
      const int col = c * 16 + rl;
      w1c[c] = (col < FH_) ? wv1[hh * FH_ + col] : 0.f;
      w2c[c] = (col < FH_) ? wv2[hh * FH_ + col] : 0.f;
    }
    #pragma unroll
    for (int r = 0; r < 4; ++r) {
      float srow = __shfl(acc[3][r], (q << 4) | 15);  // col 63 = denom (ones col)
      float invr = srow > 0.f ? 1.f / srow : 0.f;
      const size_t grow = (size_t)bb * N_ + n0 + q * 4 + r;
      float p1 = 0.f, p2 = 0.f;
      #pragma unroll
      for (int c = 0; c < 4; ++c) {
        const int col = c * 16 + rl;
        if (col < FH_) {
          float v = acc[c][r] * invr;
          v = v > 0.f ? v : __expf(v) - 1.f;  // ELU
          catbf[grow * KP_ + hh * FH_ + col] = f2bf(v);
          p1 += v * w1c[c];
          p2 += v * w2c[c];
        }
      }
      p1 += __shfl_xor(p1, 1); p1 += __shfl_xor(p1, 2);
      p1 += __shfl_xor(p1, 4); p1 += __shfl_xor(p1, 8);
      p2 += __shfl_xor(p2, 1); p2 += __shfl_xor(p2, 2);
      p2 += __shfl_xor(p2, 4); p2 += __shfl_xor(p2, 8);
      if (rl == 0) {
        e1p[(size_t)hh * (B_ * N_) + grow] = p1;
        e2p[(size_t)hh * (B_ * N_) + grow] = p2;
      }
    }
  }
  if (hh == 2 && t < 16) {  // zero-pad K cols 150..159 for this block's 16 rows
    const size_t grow = (size_t)bb * N_ + n0 + t;
    unsigned* zp = (unsigned*)&catbf[grow * KP_ + CAT_];
    #pragma unroll
    for (int i = 0; i < 5; ++i) zp[i] = 0u;
  }
}

// ---------- K4: Wh2 = catbf @ WoutT via MFMA (cols 0..79); fill 80..95 -------------
__global__ __launch_bounds__(256) void k4_gemm2(const unsigned short* __restrict__ catbf,
                                                const unsigned short* __restrict__ WoutT,
                                                unsigned short* __restrict__ wh2T) {
  const int t = threadIdx.x, l = t & 63, wid = t >> 6;
  const int q = l >> 4, rl = l & 15;
  const int blk = blockIdx.x;
  const int jbase = blk * 64 + wid * 16;
  f32x4 acc[5];
  #pragma unroll
  for (int nt = 0; nt < 5; ++nt) acc[nt] = (f32x4){0.f, 0.f, 0.f, 0.f};
  const unsigned short* ap = catbf + (size_t)(jbase + rl) * KP_ + q * 8;
  #pragma unroll
  for (int kk = 0; kk < 5; ++kk) {
    short8 a = *(const short8*)(ap + kk * 32);
    #pragma unroll
    for (int nt = 0; nt < 5; ++nt) {
      short8 b = *(const short8*)&WoutT[(size_t)(nt * 16 + rl) * KP_ + kk * 32 + q * 8];
      acc[nt] = __builtin_amdgcn_mfma_f32_16x16x32_bf16(a, b, acc[nt], 0, 0, 0);
    }
  }
  const int bb = blk >> 3, jt = blk & 7;
  const int j0 = jt * 64 + wid * 16 + q * 4;
  #pragma unroll
  for (int nt = 0; nt < 5; ++nt) {
    const int col = nt * 16 + rl;
    unsigned short pk[4];
    #pragma unroll
    for (int r = 0; r < 4; ++r) pk[r] = f2bf(acc[nt][r]);
    uint2 o;
    o.x = (unsigned)pk[0] | ((unsigned)pk[1] << 16);
    o.y = (unsigned)pk[2] | ((unsigned)pk[3] << 16);
    *(uint2*)&wh2T[((size_t)bb * NP_ + col) * 512 + j0] = o;
  }
  {
    const int col = 80 + (t >> 4), jq = (t & 15) * 4;
    unsigned fill = (col == 95) ? 0x3f803f80u : 0u;
    uint2 o; o.x = fill; o.y = fill;
    *(uint2*)&wh2T[((size_t)bb * NP_ + col) * 512 + jt * 64 + jq] = o;
  }
}

// ---------- K5: layer-2 attention, 16-row blocks, 4-wave j-split -------------------
__global__ __launch_bounds__(256) void k5_attn2(const unsigned short* __restrict__ wh2T,
                                                const float* __restrict__ e1p,
                                                const float* __restrict__ e2p,
                                                const u64* __restrict__ maskw,
                                                float* __restrict__ out) {
  __shared__ __align__(16) float e2s[N_];
  __shared__ __align__(16) float red[4][64][25];
  int x = (int)((blockIdx.x & 7) * 128 + (blockIdx.x >> 3));
  const int rg = x & 31;
  const int bb = x >> 5;
  const int n0 = rg * 16;
  const int t = threadIdx.x;
  const int l = t & 63, wid = t >> 6;
  const int q = l >> 4, rl = l & 15;

  for (int i = t; i < N_ / 4; i += 256) {
    float4 v0 = ((const float4*)(e2p))[(size_t)bb * 128 + i];
    float4 v1 = ((const float4*)(e2p + B_ * N_))[(size_t)bb * 128 + i];
    float4 v2 = ((const float4*)(e2p + 2 * B_ * N_))[(size_t)bb * 128 + i];
    float4 s;
    s.x = v0.x + v1.x + v2.x; s.y = v0.y + v1.y + v2.y;
    s.z = v0.z + v1.z + v2.z; s.w = v0.w + v1.w + v2.w;
    ((float4*)e2s)[i] = s;
  }
  __syncthreads();

  const int row = n0 + rl;
  const size_t gr = (size_t)bb * N_ + row;
  const float e1r = e1p[gr] + e1p[B_ * N_ + gr] + e1p[2 * B_ * N_ + gr];
  const u64* mr = maskw + gr * 8;

  f32x4 acc[6];
  #pragma unroll
  for (int c = 0; c < 6; ++c) acc[c] = (f32x4){0.f, 0.f, 0.f, 0.f};
  const unsigned short* wb = wh2T + (size_t)bb * NP_ * 512;

  #pragma unroll
  for (int tts = 0; tts < 2; ++tts) {
    const int tt = wid * 2 + tts;
    short8 bf[6][2];
    #pragma unroll
    for (int c = 0; c < 6; ++c) {
      const unsigned short* bp = wb + (size_t)(c * 16 + rl) * 512 + tt * 64 + q * 8;
      bf[c][0] = *(const short8*)bp;
      bf[c][1] = *(const short8*)(bp + 32);
    }
    u64 word = mr[tt];
    short8 af0 = build_af(e2s, e1r, word, tt * 64 + q * 8, q * 8);
    short8 af1 = build_af(e2s, e1r, word, tt * 64 + 32 + q * 8, 32 + q * 8);
    #pragma unroll
    for (int c = 0; c < 6; ++c) {
      acc[c] = __builtin_amdgcn_mfma_f32_16x16x32_bf16(af0, bf[c][0], acc[c], 0, 0, 0);
      acc[c] = __builtin_amdgcn_mfma_f32_16x16x32_bf16(af1, bf[c][1], acc[c], 0, 0, 0);
    }
  }

  #pragma unroll
  for (int c = 0; c < 6; ++c)
    #pragma unroll
    for (int r = 0; r < 4; ++r) red[wid][l][c * 4 + r] = acc[c][r];
  __syncthreads();

  if (wid == 0) {
    #pragma unroll
    for (int c = 0; c < 6; ++c)
      #pragma unroll
      for (int r = 0; r < 4; ++r)
        acc[c][r] = red[0][l][c * 4 + r] + red[1][l][c * 4 + r] +
                    red[2][l][c * 4 + r] + red[3][l][c * 4 + r];
    const size_t orow0 = (size_t)bb * N_ + n0;
    #pragma unroll
    for (int r = 0; r < 4; ++r) {
      float srow = __shfl(acc[5][r], (q << 4) | 15);  // col 95 = denom
      float invr = srow > 0.f ? 1.f / srow : 0.f;
      const size_t ob = (orow0 + q * 4 + r) * FO_;
      #pragma unroll
      for (int c = 0; c < 5; ++c) out[ob + c * 16 + rl] = acc[c][r] * invr;
    }
  }
}

extern "C" void kernel_launch(void* const* d_in, const int* in_sizes, int n_in,
                              void* d_out, int out_size, void* d_ws, size_t ws_size,
                              hipStream_t stream) {
  const float* h    = (const float*)d_in[0];
  const int*   adj  = (const int*)d_in[1];
  const float* Ws   = (const float*)d_in[2];
  const float* aa   = (const float*)d_in[3];
  const float* Wout = (const float*)d_in[4];
  const float* aout = (const float*)d_in[5];

  char* ws = (char*)d_ws;
  unsigned short* whT   = (unsigned short*)(ws + 0);         // 6,291,456
  float* e1h            = (float*)(ws + 6291456);            //   196,608
  float* e2h            = (float*)(ws + 6488064);            //   196,608
  u64*   mk             = (u64*)  (ws + 6684672);            // 1,048,576
  unsigned short* catbf = (unsigned short*)(ws + 7733248);   // 5,242,880
  unsigned short* WoutT = (unsigned short*)(ws + 12976128);  //    30,720
  float* wv1            = (float*)(ws + 13008896);
  float* wv2            = (float*)(ws + 13009920);
  float* e1p            = (float*)(ws + 13010944);           //   196,608
  float* e2p            = (float*)(ws + 13207552);           //   196,608
  unsigned short* wh2T  = (unsigned short*)(ws + 13404160);  // 3,145,728

  hipLaunchKernelGGL(kA, dim3(1280), dim3(256), 0, stream,
                     h, adj, Ws, aa, Wout, aout, whT, e1h, e2h, mk, WoutT, wv1, wv2);
  hipLaunchKernelGGL(k3s, dim3(3072), dim3(256), 0, stream,
                     whT, e1h, e2h, mk, wv1, wv2, catbf, e1p, e2p);
  hipLaunchKernelGGL(k4_gemm2, dim3(256), dim3(256), 0, stream, catbf, WoutT, wh2T);
  hipLaunchKernelGGL(k5_attn2, dim3(1024), dim3(256), 0, stream,
                     wh2T, e1p, e2p, mk, (float*)d_out);
}